// Round 13
// baseline (220.837 us; speedup 1.0000x reference)
//
#include <hip/hip_runtime.h>
#include <math.h>

// Problem constants
#define NQ     65536
#define DIM    256
#define NBATCH 512
#define KNN    200
#define NCLS   1000
#define TSELF  0.155f    // bf16-filter threshold (top-200 boundary ~0.171)
#define TSELH  0.150f    // histogram base
// bf16 dot err bound: |approx-exact| <= 2^-8*||a||*||b|| + f32 accum ~= 3.92e-3.
// EPSF is a strict upper bound on it.
#define EPSF   0.0041f

#define GM  128
#define GK  32
#define NTN (NQ / GM)    // 512 bn tiles
#define KSTEPS (DIM / GK)

// per-row candidate storage: 8 sublists, each SCAP entries. Counters padded
// to one 128B line each (R8 lesson: 16 counters/line = 165us serialization).
#define SUB   8
#define SCAP  256
#define CPAD  32

// copy blocks INTERLEAVED 1-in-5 into gemm's grid (R13): co-resident with
// gemm blocks from dispatch 0 (R12 lesson: appended blocks run serially).
#define NCOPY 512

typedef unsigned short u16;
typedef unsigned long long u64;
typedef __attribute__((ext_vector_type(8))) short short8;
typedef __attribute__((ext_vector_type(4))) float f32x4;

// out layout: [0] accuracy | [1..1+NQ*DIM) features | [..+NQ) labels | [last] ptr

__device__ __forceinline__ u16 f2bf(float x) {
  unsigned u = __float_as_uint(x);
  return (u16)((u + 0x7FFFu + ((u >> 16) & 1u)) >> 16);
}
__device__ __forceinline__ void load_lds16(const void* g, void* l) {
  __builtin_amdgcn_global_load_lds(
      (const __attribute__((address_space(1))) unsigned int*)g,
      (__attribute__((address_space(3))) unsigned int*)l, 16, 0, 0);
}
// out+1 is 4B-aligned, ≡4 (mod 16): dword, dwordx2 (8-aligned), dword
__device__ __forceinline__ void store_f4u(float* p, float4 v) {
  p[0] = v.x;
  *(float2*)(p + 1) = make_float2(v.y, v.z);
  p[3] = v.w;
}

// ---------------------------------------------------------------------------
// 0. prep: bf16 conversion (Bb from queue, Ab from batch), labels out,
//    counter zeroing, accuracy/ptr. Out-features copy lives in gemm's
//    interleaved copy blocks (R13).
// ---------------------------------------------------------------------------
__global__ __launch_bounds__(256) void prep_copy_kernel(
    const float* __restrict__ feat, const int* __restrict__ labels,
    const float* __restrict__ qf, const int* __restrict__ ql,
    const int* __restrict__ qptr,
    u16* __restrict__ Bb, u16* __restrict__ Ab,
    int* __restrict__ gcnt, float* __restrict__ out)
{
  const int idx = blockIdx.x * 256 + threadIdx.x;   // float4 index, < NQ*DIM/4
  const int ptr = qptr[0];
  const long long NFEAT = (long long)NQ * DIM;

  {
    float4 qv = ((const float4*)qf)[idx];
    ushort4 h;
    h.x = f2bf(qv.x); h.y = f2bf(qv.y); h.z = f2bf(qv.z); h.w = f2bf(qv.w);
    ((ushort4*)Bb)[idx] = h;
  }

  if (idx < NBATCH * DIM / 4) {
    float4 v = ((const float4*)feat)[idx];
    ushort4 h;
    h.x = f2bf(v.x); h.y = f2bf(v.y); h.z = f2bf(v.z); h.w = f2bf(v.w);
    ((ushort4*)Ab)[idx] = h;
  }

  if (idx < NQ) {
    int d = (idx - ptr) & (NQ - 1);
    int v = (d < NBATCH) ? labels[d] : ql[idx];
    out[1 + NFEAT + idx] = (float)v;
  }

  if (idx < NBATCH * SUB) gcnt[idx * CPAD] = 0;   // padded counters
  if (idx == 0) {
    out[0] = 0.0f;
    out[1 + NFEAT + NQ] = (float)((ptr + NBATCH) & (NQ - 1));
  }
}

// ---------------------------------------------------------------------------
// 1. bf16 filter GEMM (R9 form) + interleaved copy blocks. Grid = 2560:
//    d%5==4 -> copy block (streams 128 queue rows of out-features, with
//    batch replacement); else gemm block gid=(d/5)*4+d%5 in [0,2048).
//    Copy blocks are co-resident with gemm blocks (1-in-5 of the dispatch
//    stream) and soak gemm's idle BW (477 GB/s of 8 TB/s, R9/R12 PMC).
//    gemm epilogue appends (approx,col) to per-(row,sub) sublists via
//    line-padded counters.
// ---------------------------------------------------------------------------
__global__ __launch_bounds__(256) void gemm_mfma(
    const u16* __restrict__ A, const u16* __restrict__ B,
    uint2* __restrict__ cand, int* __restrict__ gcnt,
    const float* __restrict__ qf, const float* __restrict__ feat,
    const int* __restrict__ qptr, float* __restrict__ out)
{
  __shared__ u16 sA[2][GM][GK];
  __shared__ u16 sB[2][GM][GK];

  const int tid  = threadIdx.x;
  const int d    = blockIdx.x;

  // ---- copy block: stream out-features for 128 queue rows ----
  if ((d % 5) == 4) {
    const int cb = d / 5;                     // 0..NCOPY-1
    const int ptr = qptr[0];
    const long long base = (long long)cb * (NQ / NCOPY) * (DIM / 4);
    for (int t = tid; t < (NQ / NCOPY) * (DIM / 4); t += 256) {
      long long idx = base + t;               // global float4 index
      int r  = (int)(idx >> 6);
      int c4 = (int)(idx & 63);
      int dd = (r - ptr) & (NQ - 1);
      float4 v = (dd < NBATCH) ? ((const float4*)feat)[dd * 64 + c4]
                               : ((const float4*)qf)[idx];
      store_f4u(out + 1 + 4 * idx, v);
    }
    return;
  }

  const int gid  = (d / 5) * 4 + (d % 5);     // gemm block id, [0, 2048)
  const int wave = tid >> 6, lane = tid & 63;
  const int bm = (gid >> 3) & 3;
  const int bn = (gid & 7) | ((gid >> 5) << 3);
  const int sub = d & 7;                      // counter-spread index

  const u16* srcBase = ((wave < 2) ? (A + (size_t)bm * GM * DIM)
                                   : (B + (size_t)bn * GM * DIM))
                       + (size_t)(wave & 1) * 64 * DIM;
  const int kx = ((lane & 3) ^ ((lane >> 3) & 3)) * 8;  // swizzled k-chunk (u16)
  const u16* src = srcBase + (lane >> 2) * DIM + kx;
  u16* dst0 = ((wave < 2) ? &sA[0][0][0] : &sB[0][0][0]) + (wave & 1) * 64 * GK;
  u16* dst1 = ((wave < 2) ? &sA[1][0][0] : &sB[1][0][0]) + (wave & 1) * 64 * GK;

  const int wm = (wave & 1) * 64, wn = (wave >> 1) * 64;
  const int fr = lane & 15;
  const int fq = lane >> 4;
  const int fqx = fq ^ ((fr >> 1) & 3);   // swizzled read chunk

  f32x4 acc[4][4] = {};

  {
    const u16* s = src;
#pragma unroll
    for (int g = 0; g < 4; ++g)
      load_lds16(s + g * 16 * DIM, dst0 + g * 512);
  }
  __syncthreads();

  for (int t = 0; t < KSTEPS; ++t) {
    const int cur = t & 1;
    if (t + 1 < KSTEPS) {        // issue next tile's loads BEFORE compute
      const u16* s = src + (t + 1) * GK;
      u16* dl = cur ? dst0 : dst1;
#pragma unroll
      for (int g = 0; g < 4; ++g)
        load_lds16(s + g * 16 * DIM, dl + g * 512);
    }

    short8 a[4], b[4];
#pragma unroll
    for (int i = 0; i < 4; ++i) {
      a[i] = *(const short8*)&sA[cur][wm + i * 16 + fr][fqx * 8];
      b[i] = *(const short8*)&sB[cur][wn + i * 16 + fr][fqx * 8];
    }
#pragma unroll
    for (int i = 0; i < 4; ++i)
#pragma unroll
      for (int j = 0; j < 4; ++j)
        acc[i][j] = __builtin_amdgcn_mfma_f32_16x16x32_bf16(a[i], b[j], acc[i][j], 0, 0, 0);

    __syncthreads();
  }

  // epilogue: candidate append. D row = fq*4+r (m side), col = fr (n side)
  const int lrow0 = bm * GM + wm + fq * 4;
  const int ccol  = bn * GM + wn + fr;
#pragma unroll
  for (int i = 0; i < 4; ++i)
#pragma unroll
    for (int j = 0; j < 4; ++j)
#pragma unroll
      for (int r = 0; r < 4; ++r) {
        float v = acc[i][j][r];
        if (v > TSELF) {
          int grow = lrow0 + i * 16 + r;
          int col  = ccol + j * 16;
          int p = atomicAdd(&gcnt[(grow * SUB + sub) * CPAD], 1);
          if (p < SCAP)
            cand[((size_t)grow * SUB + sub) * SCAP + p] =
                make_uint2(__float_as_uint(v), (unsigned)col);
        }
      }
}

// ---------------------------------------------------------------------------
// 2. select (pure R9 form): wave-per-sublist dense gather; approx histogram
//    (shfl suffix scan) -> boundary edge; exact recompute only for approx >=
//    edge-2*EPSF (provably contains true top-200); direct O(nr^2/NT)
//    pairwise rank-count -> rank<KNN votes. Guard: e200 >= TSELF+EPSF proves
//    the gemm filter lost nothing. Sublist overflow or cap/guard failure ->
//    exact fallback.
// ---------------------------------------------------------------------------
#define NBSEL 2048
#define CCAP  2048
#define LCAP  1024
#define NT    512
#define NG    (NT / 8)    // 8-lane groups per block
#define NWV   (NT / 64)   // waves per block
#define BINW  ((1.001f - TSELH) / (float)NBSEL)

__global__ __launch_bounds__(NT, 4) void select_kernel(
    const uint2* __restrict__ cand, const int* __restrict__ gcnt,
    const int* __restrict__ labels,
    const int* __restrict__ qlab, const float* __restrict__ qf,
    const float* __restrict__ feat, float* __restrict__ out,
    float inv_n)
{
  __shared__ int   hist[NBSEL];
  __shared__ int   seg[NT];
  __shared__ int   wtot[NWV];
  __shared__ int   scnt[SUB];
  __shared__ float candV[CCAP];
  __shared__ int   candI[CCAP];
  __shared__ float votes[NCLS];
  __shared__ u64   ek[LCAP];
  __shared__ int   lst[LCAP];
  __shared__ float frow[DIM];
  __shared__ int   s_b, s_cnt, s_mb;
  __shared__ float s_chk;
  __shared__ u64   s_best;

  const int tid = threadIdx.x;
  const int row = blockIdx.x;

  bool fb = false;

  if (tid < DIM) frow[tid] = feat[(size_t)row * DIM + tid];
  for (int i = tid; i < NBSEL; i += NT) hist[i] = 0;
  for (int c = tid; c < NCLS; c += NT) votes[c] = 0.0f;
  if (tid < SUB) scnt[tid] = gcnt[(row * SUB + tid) * CPAD];
  if (tid == 0) { s_b = 0; s_mb = 0; s_best = 0ull; s_chk = -1.0f; s_cnt = 0; }
  __syncthreads();

  // overflow check + total count (every thread computes locally)
  int n = 0;
  {
    bool ovf = false;
#pragma unroll
    for (int s = 0; s < SUB; ++s) {
      int c = scnt[s];
      if (c > SCAP) ovf = true;
      n += c < SCAP ? c : SCAP;
    }
    if (ovf || n < KNN) fb = true;
  }

  if (!fb) {
    // ---- wave-per-sublist dense gather of (approx, col) ----
    {
      const int wv = tid >> 6, ln = tid & 63;
      int off = 0;
#pragma unroll
      for (int s = 0; s < SUB; ++s) {
        int c = scnt[s] < SCAP ? scnt[s] : SCAP;
        if (s < wv) off += c;
      }
      int c = scnt[wv] < SCAP ? scnt[wv] : SCAP;
      const uint2* rowc = cand + ((size_t)row * SUB + wv) * SCAP;
      for (int i = ln; i < c; i += 64) {
        uint2 e = rowc[i];
        candV[off + i] = __uint_as_float(e.x);
        candI[off + i] = (int)e.y;
      }
    }
    __syncthreads();

    // ---- approx histogram over (TSELH, ~1] ----
    const float SSCALE = 1.0f / BINW;
    for (int i = tid; i < n; i += NT) {
      int b = (int)((candV[i] - TSELH) * SSCALE);
      b = b < 0 ? 0 : (b > NBSEL - 1 ? NBSEL - 1 : b);
      atomicAdd(&hist[b], 1);
    }
    __syncthreads();
    // ---- suffix scan via wave shfl (2 barriers) ----
    {
      int s = 0;
#pragma unroll
      for (int i = 0; i < NBSEL / NT; ++i) s += hist[tid * (NBSEL / NT) + i];
      const int ln = tid & 63, wv = tid >> 6;
      int acc = s;
#pragma unroll
      for (int off = 1; off < 64; off <<= 1) {
        int o = __shfl_down(acc, off, 64);
        if (ln + off < 64) acc += o;
      }
      if (ln == 0) wtot[wv] = acc;   // wave suffix total
      __syncthreads();
      int addv = 0;
      for (int w = wv + 1; w < NWV; ++w) addv += wtot[w];
      seg[tid] = acc + addv;         // suffix sum from this thread's group
    }
    __syncthreads();
    { int run = (tid < NT - 1) ? seg[tid + 1] : 0;
      for (int i = tid * (NBSEL / NT) + NBSEL / NT - 1;
           i >= tid * (NBSEL / NT); --i) {
        run += hist[i];
        if (run >= KNN) { atomicMax(&s_b, i); break; }
      } }
    __syncthreads();
    const int bstarA = s_b;
    const float thresh = TSELH + (float)bstarA * BINW - 2.0f * EPSF;

    // ---- compact recompute list ----
    for (int i = tid; i < n; i += NT) {
      if (candV[i] >= thresh) {
        int p = atomicAdd(&s_mb, 1);
        if (p < LCAP) lst[p] = i;
      }
    }
    __syncthreads();
    const int nr = s_mb;
    if (nr > LCAP || nr < KNN) fb = true;
    else {
      // ---- 8-lane-group exact recompute over list, 2-deep pipelined ----
      const int sub = tid & 7;
      const int grp = tid >> 3;
      const float4* fr4 = (const float4*)frow;

      float4 b0[8];
      if (grp < nr) {
        const float4* qr = (const float4*)(qf + (size_t)candI[lst[grp]] * DIM);
#pragma unroll
        for (int it = 0; it < 8; ++it) b0[it] = qr[sub + it * 8];
      }
      for (int k = grp; k < nr; k += NG) {
        const int kn = k + NG;
        float4 b1[8];
        if (kn < nr) {
          const float4* qr = (const float4*)(qf + (size_t)candI[lst[kn]] * DIM);
#pragma unroll
          for (int it = 0; it < 8; ++it) b1[it] = qr[sub + it * 8];
        }
        float p = 0.0f;
#pragma unroll
        for (int it = 0; it < 8; ++it) {
          float4 a = fr4[sub + it * 8];   // LDS broadcast read
          p = fmaf(a.x, b0[it].x, p); p = fmaf(a.y, b0[it].y, p);
          p = fmaf(a.z, b0[it].z, p); p = fmaf(a.w, b0[it].w, p);
        }
        p += __shfl_xor(p, 1, 64);
        p += __shfl_xor(p, 2, 64);
        p += __shfl_xor(p, 4, 64);
        if (sub == 0) candV[lst[k]] = p;   // exact overwrites approx
#pragma unroll
        for (int it = 0; it < 8; ++it) b0[it] = b1[it];  // static rotate
      }
      __syncthreads();

      // ---- build exact keys ----
      for (int e = tid; e < nr; e += NT) {
        int ci = lst[e];
        ek[e] = ((u64)__float_as_uint(candV[ci]) << 32) |
                (u64)(0xFFFFFFFFu - (unsigned)candI[ci]);
      }
      __syncthreads();

      // ---- pairwise rank count: rank<KNN votes; rank==KNN-1 -> e200 ----
      for (int e = tid; e < nr; e += NT) {
        u64 ke = ek[e];
        int rank = 0;
        for (int j = 0; j < nr; ++j) rank += (ek[j] > ke);
        if (rank < KNN) {
          float v = __uint_as_float((unsigned)(ke >> 32));
          int col = (int)(0xFFFFFFFFu - (unsigned)(ke & 0xFFFFFFFFull));
          atomicAdd(&votes[qlab[col]], expf(v * (1.0f / 0.07f)));
          if (rank == KNN - 1) s_chk = v;   // exactly one writer
        }
      }
      __syncthreads();
      // filter-safety guard: e200 must clear the gemm filter by > eps
      if (s_chk < TSELF + EPSF) fb = true;   // fallback re-zeroes votes
    }
  }

  if (fb) {
    // ---- exact f32 recompute + selection over all NQ (guard path) ----
    for (int i = tid; i < NBSEL; i += NT) hist[i] = 0;
    if (tid == 0) { s_b = 0; s_cnt = 0; }
    __syncthreads();

    for (int q = tid; q < NQ; q += NT) {
      const float4* qr = (const float4*)(qf + (size_t)q * DIM);
      const float4* fr = (const float4*)frow;
      float s = 0.0f;
#pragma unroll
      for (int t = 0; t < DIM / 4; ++t) {
        float4 a = fr[t], b = qr[t];
        s = fmaf(a.x, b.x, s); s = fmaf(a.y, b.y, s);
        s = fmaf(a.z, b.z, s); s = fmaf(a.w, b.w, s);
      }
      int bin = (int)((s + 1.0f) * (NBSEL * 0.5f));
      bin = bin < 0 ? 0 : (bin > NBSEL - 1 ? NBSEL - 1 : bin);
      atomicAdd(&hist[bin], 1);
    }
    __syncthreads();

    { int s = 0;
#pragma unroll
      for (int i = 0; i < NBSEL / NT; ++i) s += hist[tid * (NBSEL / NT) + i];
      seg[tid] = s; }
    __syncthreads();
    for (int off = 1; off < NT; off <<= 1) {
      int t = (tid + off < NT) ? seg[tid + off] : 0;
      __syncthreads();
      seg[tid] += t;
      __syncthreads();
    }
    { int run = (tid < NT - 1) ? seg[tid + 1] : 0;
      for (int i = tid * (NBSEL / NT) + NBSEL / NT - 1;
           i >= tid * (NBSEL / NT); --i) {
        run += hist[i];
        if (run >= KNN) { atomicMax(&s_b, i); break; }
      } }
    __syncthreads();
    const int bstar = s_b;

    for (int q = tid; q < NQ; q += NT) {
      const float4* qr = (const float4*)(qf + (size_t)q * DIM);
      const float4* fr = (const float4*)frow;
      float s = 0.0f;
#pragma unroll
      for (int t = 0; t < DIM / 4; ++t) {
        float4 a = fr[t], b = qr[t];
        s = fmaf(a.x, b.x, s); s = fmaf(a.y, b.y, s);
        s = fmaf(a.z, b.z, s); s = fmaf(a.w, b.w, s);
      }
      int bin = (int)((s + 1.0f) * (NBSEL * 0.5f));
      bin = bin < 0 ? 0 : (bin > NBSEL - 1 ? NBSEL - 1 : bin);
      if (bin >= bstar) {
        int p = atomicAdd(&s_cnt, 1);
        if (p < CCAP) { candV[p] = s; candI[p] = q; }
      }
    }
    __syncthreads();
    int m = s_cnt < CCAP ? s_cnt : CCAP;

    int P = 256; while (P < m) P <<= 1;
    for (int i = tid; i < P; i += NT)
      if (i >= m) { candV[i] = -INFINITY; candI[i] = 0x7fffffff; }
    __syncthreads();
    for (int k = 2; k <= P; k <<= 1) {
      for (int j = k >> 1; j > 0; j >>= 1) {
        for (int i = tid; i < P; i += NT) {
          int ixj = i ^ j;
          if (ixj > i) {
            float va = candV[i], vb = candV[ixj];
            int ia = candI[i], ib = candI[ixj];
            bool aFirst = (va > vb) || (va == vb && ia < ib);
            bool up = ((i & k) == 0);
            if (up ? !aFirst : aFirst) {
              candV[i] = vb; candV[ixj] = va;
              candI[i] = ib; candI[ixj] = ia;
            }
          }
        }
        __syncthreads();
      }
    }

    for (int c = tid; c < NCLS; c += NT) votes[c] = 0.0f;
    __syncthreads();
    for (int i = tid; i < KNN; i += NT)
      atomicAdd(&votes[qlab[candI[i]]], expf(candV[i] * (1.0f / 0.07f)));
    __syncthreads();
  }

  // ---- common argmax (lowest class index on tie) + accuracy ----
  u64 key = 0ull;
  for (int c = tid; c < NCLS; c += NT) {
    u64 k2 = ((u64)__float_as_uint(votes[c]) << 32) |
             (u64)(0xFFFFFFFFu - (unsigned)c);
    if (k2 > key) key = k2;
  }
  for (int off = 32; off > 0; off >>= 1) {
    u64 o = __shfl_down(key, off, 64);
    if (o > key) key = o;
  }
  if ((tid & 63) == 0) atomicMax(&s_best, key);
  __syncthreads();
  if (tid == 0) {
    int cls = (int)(0xFFFFFFFFu - (unsigned)(s_best & 0xFFFFFFFFull));
    if (cls == labels[row]) atomicAdd(out, inv_n);
  }
}

// ---------------------------------------------------------------------------
extern "C" void kernel_launch(void* const* d_in, const int* in_sizes, int n_in,
                              void* d_out, int out_size, void* d_ws, size_t ws_size,
                              hipStream_t stream)
{
  const float* features = (const float*)d_in[0];
  const int*   labels   = (const int*)d_in[1];
  const float* qfeat    = (const float*)d_in[2];
  const int*   qlab     = (const int*)d_in[3];
  const int*   qptr     = (const int*)d_in[4];
  float* out = (float*)d_out;

  int nbatch = in_sizes[0] / DIM;             // 512
  float inv_n = 1.0f / (float)nbatch;

  // ws layout: [B 32MB][cand 8MB (512 x 8 x 256 x uint2)][gcnt 512KB][A 256KB]
  size_t bBytes = (size_t)NQ * DIM * 2;                 // 32 MiB
  u16*   Bb   = (u16*)d_ws;
  uint2* cand = (uint2*)((char*)d_ws + bBytes);
  int*   gcnt = (int*)((char*)cand + (size_t)NBATCH * SUB * SCAP * 8);
  u16*   Ab   = (u16*)(gcnt + (size_t)NBATCH * SUB * CPAD);

  prep_copy_kernel<<<NQ * DIM / 4 / 256, 256, 0, stream>>>(
      features, labels, qfeat, qlab, qptr, Bb, Ab, gcnt, out);

  // 2048 gemm blocks + 512 copy blocks, interleaved 1-in-5
  gemm_mfma<<<(NBATCH / GM) * (NQ / GM) / 4 * 5, 256, 0, stream>>>(
      Ab, Bb, cand, gcnt, qfeat, features, qptr, out);

  select_kernel<<<nbatch, NT, 0, stream>>>(cand, gcnt, labels, qlab,
                                           qfeat, features, out, inv_n);
}

// Round 14
// 200.588 us; speedup vs baseline: 1.1009x; 1.1009x over previous
//
#include <hip/hip_runtime.h>
#include <math.h>

// Problem constants
#define NQ     65536
#define DIM    256
#define NBATCH 512
#define KNN    200
#define NCLS   1000
#define TSELF  0.155f    // bf16-filter threshold (top-200 boundary ~0.171)
#define TSELH  0.150f    // histogram base
// bf16 dot err bound: |approx-exact| <= 2^-8*||a||*||b|| + f32 accum ~= 4.0e-3.
#define EPSF   0.0041f
// Guard: exact boundary bin must have lower edge >= TSELF + EPSF, i.e.
// bstar >= ceil((TSELF+0.0041-TSELH)/binw) = 22, else exact fallback.
#define BGUARD 22

#define GM  128
#define GK  32
#define NTN (NQ / GM)    // 512 bn tiles
#define KSTEPS (DIM / GK)

typedef unsigned short u16;
typedef unsigned long long u64;
typedef __attribute__((ext_vector_type(8))) short short8;
typedef __attribute__((ext_vector_type(4))) float f32x4;

// out layout: [0] accuracy | [1..1+NQ*DIM) features | [..+NQ) labels | [last] ptr

__device__ __forceinline__ u16 f2bf(float x) {
  unsigned u = __float_as_uint(x);
  return (u16)((u + 0x7FFFu + ((u >> 16) & 1u)) >> 16);
}
__device__ __forceinline__ void load_lds16(const void* g, void* l) {
  __builtin_amdgcn_global_load_lds(
      (const __attribute__((address_space(1))) unsigned int*)g,
      (__attribute__((address_space(3))) unsigned int*)l, 16, 0, 0);
}
// out+1 is 4B-aligned, ≡4 (mod 16): dword, dwordx2 (8-aligned), dword
__device__ __forceinline__ void store_f4u(float* p, float4 v) {
  p[0] = v.x;
  *(float2*)(p + 1) = make_float2(v.y, v.z);
  p[3] = v.w;
}

// ---------------------------------------------------------------------------
// 0. fused prep + queue-update copy.
// ---------------------------------------------------------------------------
__global__ __launch_bounds__(256) void prep_copy_kernel(
    const float* __restrict__ feat, const int* __restrict__ labels,
    const float* __restrict__ qf, const int* __restrict__ ql,
    const int* __restrict__ qptr,
    u16* __restrict__ Bb, u16* __restrict__ Ab,
    int* __restrict__ flag, float* __restrict__ out)
{
  const int idx = blockIdx.x * 256 + threadIdx.x;   // float4 index, < NQ*DIM/4
  const int ptr = qptr[0];
  const long long NFEAT = (long long)NQ * DIM;

  {
    float4 qv = ((const float4*)qf)[idx];
    int row = idx >> 6;                 // / (DIM/4)
    int c4  = idx & 63;
    int d = (row - ptr) & (NQ - 1);
    float4 ov = qv;
    if (d < NBATCH) ov = ((const float4*)feat)[d * 64 + c4];
    store_f4u(out + 1 + 4 * (long long)idx, ov);

    ushort4 h;
    h.x = f2bf(qv.x); h.y = f2bf(qv.y); h.z = f2bf(qv.z); h.w = f2bf(qv.w);
    ((ushort4*)Bb)[idx] = h;
  }

  if (idx < NBATCH * DIM / 4) {
    float4 v = ((const float4*)feat)[idx];
    ushort4 h;
    h.x = f2bf(v.x); h.y = f2bf(v.y); h.z = f2bf(v.z); h.w = f2bf(v.w);
    ((ushort4*)Ab)[idx] = h;
  }

  if (idx < NQ) {
    int d = (idx - ptr) & (NQ - 1);
    int v = (d < NBATCH) ? labels[d] : ql[idx];
    out[1 + NFEAT + idx] = (float)v;
  }

  if (idx < NBATCH) flag[idx] = 0;
  if (idx == 0) {
    out[0] = 0.0f;
    out[1 + NFEAT + NQ] = (float)((ptr + NBATCH) & (NQ - 1));
  }
}

// ---------------------------------------------------------------------------
// 1. bf16 filter GEMM, double-buffered LDS, 2-phase prefetch, bank swizzle.
//    Epilogue stores (approx value, col) as uint2 — approx guides select's
//    targeted exact recompute.
// ---------------------------------------------------------------------------
__global__ __launch_bounds__(256) void gemm_mfma(
    const u16* __restrict__ A, const u16* __restrict__ B,
    uint2* __restrict__ cand, int* __restrict__ cnt2,
    int* __restrict__ flag, int SLOT)
{
  __shared__ u16 sA[2][GM][GK];
  __shared__ u16 sB[2][GM][GK];
  __shared__ int lcnt[GM];

  const int tid  = threadIdx.x;
  const int wave = tid >> 6, lane = tid & 63;
  const int d  = blockIdx.x;
  const int bm = (d >> 3) & 3;
  const int bn = (d & 7) | ((d >> 5) << 3);

  for (int i = tid; i < GM; i += 256) lcnt[i] = 0;   // visible after 1st barrier

  const u16* srcBase = ((wave < 2) ? (A + (size_t)bm * GM * DIM)
                                   : (B + (size_t)bn * GM * DIM))
                       + (size_t)(wave & 1) * 64 * DIM;
  const int kx = ((lane & 3) ^ ((lane >> 3) & 3)) * 8;  // swizzled k-chunk (u16)
  const u16* src = srcBase + (lane >> 2) * DIM + kx;
  u16* dst0 = ((wave < 2) ? &sA[0][0][0] : &sB[0][0][0]) + (wave & 1) * 64 * GK;
  u16* dst1 = ((wave < 2) ? &sA[1][0][0] : &sB[1][0][0]) + (wave & 1) * 64 * GK;

  const int wm = (wave & 1) * 64, wn = (wave >> 1) * 64;
  const int fr = lane & 15;
  const int fq = lane >> 4;
  const int fqx = fq ^ ((fr >> 1) & 3);   // swizzled read chunk

  f32x4 acc[4][4] = {};

  {
    const u16* s = src;
#pragma unroll
    for (int g = 0; g < 4; ++g)
      load_lds16(s + g * 16 * DIM, dst0 + g * 512);
  }
  __syncthreads();

  for (int t = 0; t < KSTEPS; ++t) {
    const int cur = t & 1;
    if (t + 1 < KSTEPS) {        // issue next tile's loads BEFORE compute
      const u16* s = src + (t + 1) * GK;
      u16* dl = cur ? dst0 : dst1;
#pragma unroll
      for (int g = 0; g < 4; ++g)
        load_lds16(s + g * 16 * DIM, dl + g * 512);
    }

    short8 a[4], b[4];
#pragma unroll
    for (int i = 0; i < 4; ++i) {
      a[i] = *(const short8*)&sA[cur][wm + i * 16 + fr][fqx * 8];
      b[i] = *(const short8*)&sB[cur][wn + i * 16 + fr][fqx * 8];
    }
#pragma unroll
    for (int i = 0; i < 4; ++i)
#pragma unroll
      for (int j = 0; j < 4; ++j)
        acc[i][j] = __builtin_amdgcn_mfma_f32_16x16x32_bf16(a[i], b[j], acc[i][j], 0, 0, 0);

    __syncthreads();
  }

  // epilogue: D row = fq*4+r (m side), col = fr (n side)
  const int lrow0 = wm + fq * 4;
  const int ccol  = bn * GM + wn + fr;
#pragma unroll
  for (int i = 0; i < 4; ++i)
#pragma unroll
    for (int j = 0; j < 4; ++j)
#pragma unroll
      for (int r = 0; r < 4; ++r) {
        float v = acc[i][j][r];
        if (v > TSELF) {
          int lr  = lrow0 + i * 16 + r;
          int col = ccol + j * 16;
          int p = atomicAdd(&lcnt[lr], 1);
          if (p < SLOT)
            cand[((size_t)(bm * GM + lr) * NTN + bn) * SLOT + p] =
                make_uint2(__float_as_uint(v), (unsigned)col);
          else
            flag[bm * GM + lr] = 1;
        }
      }
  __syncthreads();
  if (tid < GM) {
    int c = lcnt[tid];
    cnt2[(size_t)(bm * GM + tid) * NTN + bn] = c < SLOT ? c : SLOT;
  }
}

// ---------------------------------------------------------------------------
// 2. select: gather (approx,col); approx histogram -> provisional boundary
//    b*_a; EXACT recompute only for candidates with approx >= edge(b*_a)-2eps
//    (provably contains true top-200); exact histogram + boundary-bin rank +
//    vote on exact values. Guards: BGUARD, list/cap overflows -> exact
//    full-recompute fallback.
// ---------------------------------------------------------------------------
#define NBSEL 2048
#define CCAP  2048
#define MBCAP 256
#define LCAP  1024
#define NT    512
#define NG    (NT / 8)    // 8-lane groups per block
#define BINW  ((1.001f - TSELH) / (float)NBSEL)

__global__ __launch_bounds__(NT, 4) void select_kernel(
    const uint2* __restrict__ cand, const int* __restrict__ cnt2,
    const int* __restrict__ flag, const int* __restrict__ labels,
    const int* __restrict__ qlab, const float* __restrict__ qf,
    const float* __restrict__ feat, float* __restrict__ out,
    float inv_n, int SLOT)
{
  __shared__ int   hist[NBSEL];
  __shared__ int   seg[NT];
  __shared__ float candV[CCAP];
  __shared__ int   candI[CCAP];
  __shared__ float votes[NCLS];
  __shared__ u64   bk[LCAP / 2];     // doubles as int list[LCAP] for compaction
  __shared__ float frow[DIM];
  __shared__ int   s_b, s_cnt, s_hi, s_mb;
  __shared__ u64   s_best;

  const int tid = threadIdx.x;
  const int row = blockIdx.x;

  bool fb = (flag[row] != 0);           // block-uniform

  if (tid < DIM) frow[tid] = feat[(size_t)row * DIM + tid];
  for (int i = tid; i < NBSEL; i += NT) hist[i] = 0;
  for (int c = tid; c < NCLS; c += NT) votes[c] = 0.0f;
  if (tid == 0) { s_b = 0; s_cnt = 0; s_hi = 0; s_mb = 0; s_best = 0ull; }
  __syncthreads();

  if (!fb) {
    // ---- gather (approx, col) from slotted lists ----
    const int*   rowcnt  = cnt2 + (size_t)row * NTN;
    const uint2* rowcand = cand + (size_t)row * NTN * SLOT;
    for (int t = tid; t < NTN; t += NT) {
      int c = rowcnt[t];
      if (c > 0) {
        int p = atomicAdd(&s_cnt, c);
        for (int k = 0; k < c; ++k) {
          if (p + k < CCAP) {
            uint2 e = rowcand[(size_t)t * SLOT + k];
            candV[p + k] = __uint_as_float(e.x);
            candI[p + k] = (int)e.y;
          }
        }
      }
    }
    __syncthreads();
    const int n = s_cnt;
    if (n < KNN || n > CCAP) fb = true;
    else {
      // ---- approx histogram over (TSELH, ~1] ----
      const float SSCALE = 1.0f / BINW;
      for (int i = tid; i < n; i += NT) {
        int b = (int)((candV[i] - TSELH) * SSCALE);
        b = b < 0 ? 0 : (b > NBSEL - 1 ? NBSEL - 1 : b);
        atomicAdd(&hist[b], 1);
      }
      __syncthreads();
      { int s = 0;
#pragma unroll
        for (int i = 0; i < NBSEL / NT; ++i) s += hist[tid * (NBSEL / NT) + i];
        seg[tid] = s; }
      __syncthreads();
      for (int off = 1; off < NT; off <<= 1) {
        int t = (tid + off < NT) ? seg[tid + off] : 0;
        __syncthreads();
        seg[tid] += t;
        __syncthreads();
      }
      { int run = (tid < NT - 1) ? seg[tid + 1] : 0;
        for (int i = tid * (NBSEL / NT) + NBSEL / NT - 1;
             i >= tid * (NBSEL / NT); --i) {
          run += hist[i];
          if (run >= KNN) { atomicMax(&s_b, i); break; }
        } }
      __syncthreads();
      const int bstarA = s_b;
      const float thresh = TSELH + (float)bstarA * BINW - 2.0f * EPSF;

      // ---- re-zero hist, compact recompute list ----
      int* lst = (int*)bk;
      for (int i = tid; i < NBSEL; i += NT) hist[i] = 0;
      if (tid == 0) s_b = 0;
      for (int i = tid; i < n; i += NT) {
        if (candV[i] >= thresh) {
          int p = atomicAdd(&s_mb, 1);
          if (p < LCAP) lst[p] = i;
        }
      }
      __syncthreads();
      const int nr = s_mb;
      if (nr > LCAP) fb = true;
      else {
        // ---- 8-lane-group exact recompute over list, 2-deep pipelined ----
        const int sub = tid & 7;
        const int grp = tid >> 3;
        const float4* fr4 = (const float4*)frow;

        float4 b0[8];
        if (grp < nr) {
          const float4* qr = (const float4*)(qf + (size_t)candI[lst[grp]] * DIM);
#pragma unroll
          for (int it = 0; it < 8; ++it) b0[it] = qr[sub + it * 8];
        }
        for (int k = grp; k < nr; k += NG) {
          const int kn = k + NG;
          float4 b1[8];
          if (kn < nr) {
            const float4* qr = (const float4*)(qf + (size_t)candI[lst[kn]] * DIM);
#pragma unroll
            for (int it = 0; it < 8; ++it) b1[it] = qr[sub + it * 8];
          }
          float p = 0.0f;
#pragma unroll
          for (int it = 0; it < 8; ++it) {
            float4 a = fr4[sub + it * 8];   // LDS broadcast read
            p = fmaf(a.x, b0[it].x, p); p = fmaf(a.y, b0[it].y, p);
            p = fmaf(a.z, b0[it].z, p); p = fmaf(a.w, b0[it].w, p);
          }
          p += __shfl_xor(p, 1, 64);
          p += __shfl_xor(p, 2, 64);
          p += __shfl_xor(p, 4, 64);
          if (sub == 0) candV[lst[k]] = p;   // exact overwrites approx
#pragma unroll
          for (int it = 0; it < 8; ++it) b0[it] = b1[it];  // static rotate
        }
        if (tid == 0) s_mb = 0;              // reuse for boundary collection
        __syncthreads();

        // ---- exact histogram (included = candV >= thresh) ----
        for (int i = tid; i < n; i += NT) {
          float v = candV[i];
          if (v >= thresh) {
            int b = (int)((v - TSELH) * SSCALE);
            b = b < 0 ? 0 : (b > NBSEL - 1 ? NBSEL - 1 : b);
            atomicAdd(&hist[b], 1);
          }
        }
        __syncthreads();
        { int s = 0;
#pragma unroll
          for (int i = 0; i < NBSEL / NT; ++i) s += hist[tid * (NBSEL / NT) + i];
          seg[tid] = s; }
        __syncthreads();
        for (int off = 1; off < NT; off <<= 1) {
          int t = (tid + off < NT) ? seg[tid + off] : 0;
          __syncthreads();
          seg[tid] += t;
          __syncthreads();
        }
        { int run = (tid < NT - 1) ? seg[tid + 1] : 0;
          for (int i = tid * (NBSEL / NT) + NBSEL / NT - 1;
               i >= tid * (NBSEL / NT); --i) {
            run += hist[i];
            if (run >= KNN) { atomicMax(&s_b, i); break; }
          } }
        __syncthreads();
        const int bstar = s_b;

        if (bstar < BGUARD) fb = true;   // filter-safety not provable
        else {
          // ---- vote bins > b*, collect bin-b* elements ----
          for (int i = tid; i < n; i += NT) {
            float v = candV[i];
            if (v < thresh) continue;
            int b = (int)((v - TSELH) * SSCALE);
            b = b < 0 ? 0 : (b > NBSEL - 1 ? NBSEL - 1 : b);
            if (b > bstar) {
              atomicAdd(&s_hi, 1);
              atomicAdd(&votes[qlab[candI[i]]], expf(v * (1.0f / 0.07f)));
            } else if (b == bstar) {
              int p = atomicAdd(&s_mb, 1);
              if (p < MBCAP)
                bk[p] = ((u64)__float_as_uint(v) << 32) |
                        (u64)(0xFFFFFFFFu - (unsigned)candI[i]);
            }
          }
          __syncthreads();
          const int mb = s_mb;
          if (mb > MBCAP) fb = true;   // fallback re-zeroes votes, so safe
          else {
            const int need = KNN - s_hi;   // 1 <= need <= mb by construction
            for (int e = tid; e < mb; e += NT) {
              u64 ke = bk[e];
              int rank = 0;
              for (int j = 0; j < mb; ++j) rank += (bk[j] > ke);
              if (rank < need) {
                float v = __uint_as_float((unsigned)(ke >> 32));
                int col = (int)(0xFFFFFFFFu - (unsigned)(ke & 0xFFFFFFFFull));
                atomicAdd(&votes[qlab[col]], expf(v * (1.0f / 0.07f)));
              }
            }
            __syncthreads();
          }
        }
      }
    }
  }

  if (fb) {
    // ---- exact f32 recompute + selection over all NQ (guard path) ----
    for (int i = tid; i < NBSEL; i += NT) hist[i] = 0;
    if (tid == 0) { s_b = 0; s_cnt = 0; }
    __syncthreads();

    for (int q = tid; q < NQ; q += NT) {
      const float4* qr = (const float4*)(qf + (size_t)q * DIM);
      const float4* fr = (const float4*)frow;
      float s = 0.0f;
#pragma unroll
      for (int t = 0; t < DIM / 4; ++t) {
        float4 a = fr[t], b = qr[t];
        s = fmaf(a.x, b.x, s); s = fmaf(a.y, b.y, s);
        s = fmaf(a.z, b.z, s); s = fmaf(a.w, b.w, s);
      }
      int bin = (int)((s + 1.0f) * (NBSEL * 0.5f));
      bin = bin < 0 ? 0 : (bin > NBSEL - 1 ? NBSEL - 1 : bin);
      atomicAdd(&hist[bin], 1);
    }
    __syncthreads();

    { int s = 0;
#pragma unroll
      for (int i = 0; i < NBSEL / NT; ++i) s += hist[tid * (NBSEL / NT) + i];
      seg[tid] = s; }
    __syncthreads();
    for (int off = 1; off < NT; off <<= 1) {
      int t = (tid + off < NT) ? seg[tid + off] : 0;
      __syncthreads();
      seg[tid] += t;
      __syncthreads();
    }
    { int run = (tid < NT - 1) ? seg[tid + 1] : 0;
      for (int i = tid * (NBSEL / NT) + NBSEL / NT - 1;
           i >= tid * (NBSEL / NT); --i) {
        run += hist[i];
        if (run >= KNN) { atomicMax(&s_b, i); break; }
      } }
    __syncthreads();
    const int bstar = s_b;

    for (int q = tid; q < NQ; q += NT) {
      const float4* qr = (const float4*)(qf + (size_t)q * DIM);
      const float4* fr = (const float4*)frow;
      float s = 0.0f;
#pragma unroll
      for (int t = 0; t < DIM / 4; ++t) {
        float4 a = fr[t], b = qr[t];
        s = fmaf(a.x, b.x, s); s = fmaf(a.y, b.y, s);
        s = fmaf(a.z, b.z, s); s = fmaf(a.w, b.w, s);
      }
      int bin = (int)((s + 1.0f) * (NBSEL * 0.5f));
      bin = bin < 0 ? 0 : (bin > NBSEL - 1 ? NBSEL - 1 : bin);
      if (bin >= bstar) {
        int p = atomicAdd(&s_cnt, 1);
        if (p < CCAP) { candV[p] = s; candI[p] = q; }
      }
    }
    __syncthreads();
    int m = s_cnt < CCAP ? s_cnt : CCAP;

    int P = 256; while (P < m) P <<= 1;
    for (int i = tid; i < P; i += NT)
      if (i >= m) { candV[i] = -INFINITY; candI[i] = 0x7fffffff; }
    __syncthreads();
    for (int k = 2; k <= P; k <<= 1) {
      for (int j = k >> 1; j > 0; j >>= 1) {
        for (int i = tid; i < P; i += NT) {
          int ixj = i ^ j;
          if (ixj > i) {
            float va = candV[i], vb = candV[ixj];
            int ia = candI[i], ib = candI[ixj];
            bool aFirst = (va > vb) || (va == vb && ia < ib);
            bool up = ((i & k) == 0);
            if (up ? !aFirst : aFirst) {
              candV[i] = vb; candV[ixj] = va;
              candI[i] = ib; candI[ixj] = ia;
            }
          }
        }
        __syncthreads();
      }
    }

    for (int c = tid; c < NCLS; c += NT) votes[c] = 0.0f;
    __syncthreads();
    for (int i = tid; i < KNN; i += NT)
      atomicAdd(&votes[qlab[candI[i]]], expf(candV[i] * (1.0f / 0.07f)));
    __syncthreads();
  }

  // ---- common argmax (lowest class index on tie) + accuracy ----
  u64 key = 0ull;
  for (int c = tid; c < NCLS; c += NT) {
    u64 k2 = ((u64)__float_as_uint(votes[c]) << 32) |
             (u64)(0xFFFFFFFFu - (unsigned)c);
    if (k2 > key) key = k2;
  }
  for (int off = 32; off > 0; off >>= 1) {
    u64 o = __shfl_down(key, off, 64);
    if (o > key) key = o;
  }
  if ((tid & 63) == 0) atomicMax(&s_best, key);
  __syncthreads();
  if (tid == 0) {
    int cls = (int)(0xFFFFFFFFu - (unsigned)(s_best & 0xFFFFFFFFull));
    if (cls == labels[row]) atomicAdd(out, inv_n);
  }
}

// ---------------------------------------------------------------------------
extern "C" void kernel_launch(void* const* d_in, const int* in_sizes, int n_in,
                              void* d_out, int out_size, void* d_ws, size_t ws_size,
                              hipStream_t stream)
{
  const float* features = (const float*)d_in[0];
  const int*   labels   = (const int*)d_in[1];
  const float* qfeat    = (const float*)d_in[2];
  const int*   qlab     = (const int*)d_in[3];
  const int*   qptr     = (const int*)d_in[4];
  float* out = (float*)d_out;

  int nbatch = in_sizes[0] / DIM;             // 512
  float inv_n = 1.0f / (float)nbatch;

  // ws layout: [B 32MB][cand uint2][cnt2 1MB][flag 2KB][A 256KB]
  size_t bBytes = (size_t)NQ * DIM * 2;                 // 32 MiB
  size_t fixed  = bBytes + (size_t)NBATCH * NTN * 4 + NBATCH * 4 +
                  (size_t)NBATCH * DIM * 2;
  int SLOT = 16;
  while ((size_t)NBATCH * NTN * SLOT * 8 + fixed > ws_size && SLOT > 2) SLOT >>= 1;

  u16*   Bb   = (u16*)d_ws;
  uint2* cand = (uint2*)((char*)d_ws + bBytes);
  int*   cnt2 = (int*)((char*)cand + (size_t)NBATCH * NTN * SLOT * 8);
  int*   flagp = cnt2 + (size_t)NBATCH * NTN;
  u16*   Ab   = (u16*)(flagp + NBATCH);

  prep_copy_kernel<<<NQ * DIM / 4 / 256, 256, 0, stream>>>(
      features, labels, qfeat, qlab, qptr, Bb, Ab, flagp, out);

  gemm_mfma<<<(NBATCH / GM) * (NQ / GM), 256, 0, stream>>>(
      Ab, Bb, cand, cnt2, flagp, SLOT);

  select_kernel<<<nbatch, NT, 0, stream>>>(cand, cnt2, flagp, labels, qlab,
                                           qfeat, features, out, inv_n, SLOT);
}